// Round 2
// baseline (638.397 us; speedup 1.0000x reference)
//
#include <hip/hip_runtime.h>

// ---------------------------------------------------------------------------
// MQA forward: out = OutProj( MHA( x·Wq^T, x·Wk^T, x·Wv^T ) )
// B=2, L=2048, D=2048, H=16, dh=128 (MQA: K/V shared across heads)
// R2: attn rewrite — 16 q-rows/wave (2x occupancy), KVBLK=64, defer-rescale
// (THR=8 log2), exp2 with folded log2e, padded P-tile; K+V proj fused.
// ---------------------------------------------------------------------------

typedef __attribute__((ext_vector_type(8))) short bf16x8;
typedef __attribute__((ext_vector_type(4))) short short4v;
typedef __attribute__((ext_vector_type(4))) float f32x4;

__device__ __forceinline__ unsigned short f2bf(float f) {
  unsigned int u = __builtin_bit_cast(unsigned int, f);
  u += 0x7fffu + ((u >> 16) & 1u);  // RNE (finite inputs only)
  return (unsigned short)(u >> 16);
}

typedef __attribute__((address_space(1))) void gvoid_t;
typedef __attribute__((address_space(3))) void lvoid_t;

__device__ __forceinline__ void gll16(const void* g, void* l) {
  __builtin_amdgcn_global_load_lds((gvoid_t*)g, (lvoid_t*)l, 16, 0, 0);
}

// ---------------------------------------------------------------------------
// fp32 -> bf16 cast, vectorized 4-wide
// ---------------------------------------------------------------------------
__global__ void cast_bf16_kernel(const float* __restrict__ in,
                                 unsigned short* __restrict__ out, int n4) {
  int i = blockIdx.x * blockDim.x + threadIdx.x;
  int stride = gridDim.x * blockDim.x;
  for (; i < n4; i += stride) {
    float4 f = reinterpret_cast<const float4*>(in)[i];
    short4v o;
    o.x = (short)f2bf(f.x);
    o.y = (short)f2bf(f.y);
    o.z = (short)f2bf(f.z);
    o.w = (short)f2bf(f.w);
    reinterpret_cast<short4v*>(out)[i] = o;
  }
}

// ---------------------------------------------------------------------------
// GEMM: C[M,N] = A[M,K] · B[N,K]^T   (bf16 in, fp32 acc)
// 128x128 tile, BK=32, 4 waves (each 64x64 = 4x4 fragments of 16x16x32).
// MODE 0: bf16 store C[m*N+n] * scale
// MODE 2: fp32 store C[m*N+n] + bias[n]
// MODE 3: col<128 -> bf16 K store (stride 128); col>=128 -> bf16 V^T store
// ---------------------------------------------------------------------------
template <int MODE>
__global__ __launch_bounds__(256) void gemm_bt(
    const unsigned short* __restrict__ A, const unsigned short* __restrict__ B,
    void* __restrict__ Cout, int M, int N, int K, float scale,
    const float* __restrict__ bias, void* __restrict__ C2) {
  __shared__ unsigned short As[128 * 32] __attribute__((aligned(16)));
  __shared__ unsigned short Bs[128 * 32] __attribute__((aligned(16)));

  const int tid = threadIdx.x;
  const int lane = tid & 63;
  const int wave = tid >> 6;
  const int lr = lane & 15;
  const int lg = lane >> 4;
  const int bm = blockIdx.x * 128;
  const int bn = blockIdx.y * 128;
  const int wrow = (wave >> 1) * 64;
  const int wcol = (wave & 1) * 64;

  f32x4 acc[4][4] = {};

  const int c0 = tid;
  const int c1 = tid + 256;

  for (int k0 = 0; k0 < K; k0 += 32) {
    __syncthreads();
    gll16(A + (size_t)(bm + (c0 >> 2)) * K + k0 + (c0 & 3) * 8,
          (char*)As + wave * 1024);
    gll16(A + (size_t)(bm + (c1 >> 2)) * K + k0 + (c1 & 3) * 8,
          (char*)As + 4096 + wave * 1024);
    gll16(B + (size_t)(bn + (c0 >> 2)) * K + k0 + (c0 & 3) * 8,
          (char*)Bs + wave * 1024);
    gll16(B + (size_t)(bn + (c1 >> 2)) * K + k0 + (c1 & 3) * 8,
          (char*)Bs + 4096 + wave * 1024);
    __syncthreads();

    bf16x8 af[4], bfr[4];
#pragma unroll
    for (int mi = 0; mi < 4; mi++)
      af[mi] = *(const bf16x8*)&As[(wrow + mi * 16 + lr) * 32 + 8 * lg];
#pragma unroll
    for (int nj = 0; nj < 4; nj++)
      bfr[nj] = *(const bf16x8*)&Bs[(wcol + nj * 16 + lr) * 32 + 8 * lg];
#pragma unroll
    for (int mi = 0; mi < 4; mi++)
#pragma unroll
      for (int nj = 0; nj < 4; nj++)
        acc[mi][nj] = __builtin_amdgcn_mfma_f32_16x16x32_bf16(
            af[mi], bfr[nj], acc[mi][nj], 0, 0, 0);
  }

#pragma unroll
  for (int mi = 0; mi < 4; mi++)
#pragma unroll
    for (int nj = 0; nj < 4; nj++) {
      const int row = bm + wrow + mi * 16 + lg * 4;
      const int col = bn + wcol + nj * 16 + lr;
#pragma unroll
      for (int r = 0; r < 4; r++) {
        float v = acc[mi][nj][r] * scale;
        if constexpr (MODE == 0) {
          ((unsigned short*)Cout)[(size_t)(row + r) * N + col] = f2bf(v);
        } else if constexpr (MODE == 2) {
          ((float*)Cout)[(size_t)(row + r) * N + col] = v + bias[col];
        } else {  // MODE 3: fused K / V^T epilogue
          if (col < 128)
            ((unsigned short*)Cout)[(size_t)(row + r) * 128 + col] = f2bf(v);
          else
            ((unsigned short*)C2)[(size_t)(col - 128) * M + (row + r)] =
                f2bf(v);
        }
      }
    }
}

// ---------------------------------------------------------------------------
// Flash-style MQA attention, v2.
// Q: [B*L, 2048] bf16 pre-scaled by log2(e)/sqrt(dh)  (exp2-domain logits)
// K: [B*L, 128] bf16 ; VT: [128, B*L] bf16
// O: [B*L, 2048] bf16
// Block 256 = 4 waves; each wave owns 16 q-rows of one (b,h). KVBLK=64.
// grid: (L/64, B*H) = (32, 32)
// ---------------------------------------------------------------------------
__global__ __launch_bounds__(256) void mqa_attn(
    const unsigned short* __restrict__ Q, const unsigned short* __restrict__ Kb,
    const unsigned short* __restrict__ VT, unsigned short* __restrict__ Ob) {
  // per-wave P tile: 16 rows x 64 cols, row stride 72 shorts (144B, 16B-align)
  __shared__ unsigned short ldsP[4][16][72] __attribute__((aligned(16)));

  const int lane = threadIdx.x & 63;
  const int wave = threadIdx.x >> 6;
  const int lr = lane & 15;
  const int lg = lane >> 4;
  const int bh = blockIdx.y;
  const int b = bh >> 4;
  const int h = bh & 15;
  const int q0 = blockIdx.x * 64 + wave * 16;

  const unsigned short* Qb = Q + ((size_t)(b * 2048 + q0)) * 2048 + h * 128;
  const unsigned short* Kbase = Kb + (size_t)b * 2048 * 128;
  const unsigned short* VTb = VT + (size_t)b * 2048;

  // Q fragments: A[m=q][k=d], lane: m=lr, k=8*lg+i
  bf16x8 qf[4];
#pragma unroll
  for (int ks = 0; ks < 4; ks++)
    qf[ks] = *(const bf16x8*)&Qb[(size_t)lr * 2048 + ks * 32 + 8 * lg];

  f32x4 oacc[8] = {};
  float mrun[4], lrun[4];
#pragma unroll
  for (int r = 0; r < 4; r++) {
    mrun[r] = -1e30f;
    lrun[r] = 0.0f;
  }

  for (int kv0 = 0; kv0 < 2048; kv0 += 64) {
    // S = Q·K^T over 64 kv cols: s[nj], cols kv0 + nj*16 + lr, rows lg*4+r
    f32x4 s[4];
#pragma unroll
    for (int nj = 0; nj < 4; nj++) {
      const unsigned short* kp =
          &Kbase[(size_t)(kv0 + nj * 16 + lr) * 128 + 8 * lg];
      f32x4 z = {0.f, 0.f, 0.f, 0.f};
#pragma unroll
      for (int ks = 0; ks < 4; ks++)
        z = __builtin_amdgcn_mfma_f32_16x16x32_bf16(
            qf[ks], *(const bf16x8*)(kp + ks * 32), z, 0, 0, 0);
      s[nj] = z;
    }

    // tile max per row (logits are in log2 domain)
    float tm[4];
    bool ok = true;
#pragma unroll
    for (int r = 0; r < 4; r++) {
      float t = fmaxf(fmaxf(s[0][r], s[1][r]), fmaxf(s[2][r], s[3][r]));
      t = fmaxf(t, __shfl_xor(t, 1));
      t = fmaxf(t, __shfl_xor(t, 2));
      t = fmaxf(t, __shfl_xor(t, 4));
      t = fmaxf(t, __shfl_xor(t, 8));
      tm[r] = t;
      ok = ok && (t <= mrun[r] + 8.0f);
    }
    if (!__all(ok)) {  // rare after first tile (defer-rescale, THR=8)
#pragma unroll
      for (int r = 0; r < 4; r++) {
        float mnew = fmaxf(mrun[r], tm[r]);
        float sc = exp2f(mrun[r] - mnew);
        mrun[r] = mnew;
        lrun[r] *= sc;
#pragma unroll
        for (int dt = 0; dt < 8; dt++) oacc[dt][r] *= sc;
      }
    }

#pragma unroll
    for (int r = 0; r < 4; r++) {
      float p0 = exp2f(s[0][r] - mrun[r]);
      float p1 = exp2f(s[1][r] - mrun[r]);
      float p2 = exp2f(s[2][r] - mrun[r]);
      float p3 = exp2f(s[3][r] - mrun[r]);
      float ps = (p0 + p1) + (p2 + p3);
      ps += __shfl_xor(ps, 1);
      ps += __shfl_xor(ps, 2);
      ps += __shfl_xor(ps, 4);
      ps += __shfl_xor(ps, 8);
      lrun[r] += ps;
      ldsP[wave][lg * 4 + r][lr] = f2bf(p0);
      ldsP[wave][lg * 4 + r][16 + lr] = f2bf(p1);
      ldsP[wave][lg * 4 + r][32 + lr] = f2bf(p2);
      ldsP[wave][lg * 4 + r][48 + lr] = f2bf(p3);
    }

    // P A-frags (kv chunks 0..31, 32..63); per-wave tile, no barrier needed
    bf16x8 pa0 = *(const bf16x8*)&ldsP[wave][lr][8 * lg];
    bf16x8 pa1 = *(const bf16x8*)&ldsP[wave][lr][32 + 8 * lg];
#pragma unroll
    for (int dt = 0; dt < 8; dt++) {
      const unsigned short* vp =
          &VTb[(size_t)(dt * 16 + lr) * 4096 + kv0 + 8 * lg];
      oacc[dt] = __builtin_amdgcn_mfma_f32_16x16x32_bf16(
          pa0, *(const bf16x8*)vp, oacc[dt], 0, 0, 0);
      oacc[dt] = __builtin_amdgcn_mfma_f32_16x16x32_bf16(
          pa1, *(const bf16x8*)(vp + 32), oacc[dt], 0, 0, 0);
    }
  }

#pragma unroll
  for (int r = 0; r < 4; r++) {
    float inv = 1.0f / lrun[r];
    size_t row = (size_t)(b * 2048 + q0 + lg * 4 + r);
#pragma unroll
    for (int dt = 0; dt < 8; dt++)
      Ob[row * 2048 + h * 128 + dt * 16 + lr] = f2bf(oacc[dt][r] * inv);
  }
}

// ---------------------------------------------------------------------------
extern "C" void kernel_launch(void* const* d_in, const int* in_sizes, int n_in,
                              void* d_out, int out_size, void* d_ws,
                              size_t ws_size, hipStream_t stream) {
  const float* x = (const float*)d_in[0];
  const float* Wq = (const float*)d_in[1];
  const float* Wk = (const float*)d_in[2];
  const float* Wv = (const float*)d_in[3];
  const float* Wo = (const float*)d_in[4];
  const float* bo = (const float*)d_in[5];

  const int Bb = 2, Lq = 2048, D = 2048, DH = 128;
  const int M = Bb * Lq;  // 4096

  char* ws = (char*)d_ws;
  size_t off = 0;
  auto alloc = [&](size_t bytes) {
    void* p = ws + off;
    off += (bytes + 255) & ~size_t(255);
    return p;
  };
  unsigned short* x_bf = (unsigned short*)alloc((size_t)M * D * 2);
  unsigned short* Wq_bf = (unsigned short*)alloc((size_t)D * D * 2);
  unsigned short* Wkv_bf = (unsigned short*)alloc((size_t)2 * DH * D * 2);
  unsigned short* Wo_bf = (unsigned short*)alloc((size_t)D * D * 2);
  unsigned short* Qbuf = (unsigned short*)alloc((size_t)M * D * 2);
  unsigned short* Kbuf = (unsigned short*)alloc((size_t)M * DH * 2);
  unsigned short* VTbuf = (unsigned short*)alloc((size_t)DH * M * 2);
  unsigned short* AObuf = (unsigned short*)alloc((size_t)M * D * 2);

  auto cast = [&](const float* in, unsigned short* outp, int n) {
    int n4 = n >> 2;
    int grid = (n4 + 255) / 256;
    if (grid > 2048) grid = 2048;
    cast_bf16_kernel<<<grid, 256, 0, stream>>>(in, outp, n4);
  };
  cast(x, x_bf, M * D);
  cast(Wq, Wq_bf, D * D);
  cast(Wk, Wkv_bf, DH * D);               // rows 0..127 of fused KV weights
  cast(Wv, Wkv_bf + (size_t)DH * D, DH * D);  // rows 128..255
  cast(Wo, Wo_bf, D * D);

  // Q = x·Wq^T scaled by log2(e)/sqrt(dh): logits land in exp2 domain
  gemm_bt<0><<<dim3(M / 128, D / 128), 256, 0, stream>>>(
      x_bf, Wq_bf, Qbuf, M, D, D, 0.12752041986f, nullptr, nullptr);
  // K and V^T in one GEMM (N=256)
  gemm_bt<3><<<dim3(M / 128, 2), 256, 0, stream>>>(
      x_bf, Wkv_bf, Kbuf, M, 2 * DH, D, 1.0f, nullptr, VTbuf);
  // attention
  mqa_attn<<<dim3(Lq / 64, Bb * 16), 256, 0, stream>>>(Qbuf, Kbuf, VTbuf,
                                                       AObuf);
  // out = AO·Wo^T + bo  (fp32 output)
  gemm_bt<2><<<dim3(M / 128, D / 128), 256, 0, stream>>>(
      AObuf, Wo_bf, d_out, M, D, D, 1.0f, bo, nullptr);
}

// Round 3
// 393.746 us; speedup vs baseline: 1.6213x; 1.6213x over previous
//
#include <hip/hip_runtime.h>

// ---------------------------------------------------------------------------
// MQA forward: out = OutProj( MHA( x·Wq^T, x·Wk^T, x·Wv^T ) )
// B=2, L=2048, D=2048, H=16, dh=128 (MQA: K/V shared across heads)
// R3: attn = 4 waves/block share (b,h); K/V tiles staged in LDS via
// global_load_lds with XOR-swizzled source (T2, rule 21); 32 q-rows/wave
// (reuse!) + KVBLK=64 + defer-rescale + exp2 softmax from R2.
// ---------------------------------------------------------------------------

typedef __attribute__((ext_vector_type(8))) short bf16x8;
typedef __attribute__((ext_vector_type(4))) short short4v;
typedef __attribute__((ext_vector_type(4))) float f32x4;

__device__ __forceinline__ unsigned short f2bf(float f) {
  unsigned int u = __builtin_bit_cast(unsigned int, f);
  u += 0x7fffu + ((u >> 16) & 1u);  // RNE (finite inputs only)
  return (unsigned short)(u >> 16);
}

typedef __attribute__((address_space(1))) void gvoid_t;
typedef __attribute__((address_space(3))) void lvoid_t;

__device__ __forceinline__ void gll16(const void* g, void* l) {
  __builtin_amdgcn_global_load_lds((gvoid_t*)g, (lvoid_t*)l, 16, 0, 0);
}

// ---------------------------------------------------------------------------
// fp32 -> bf16 cast, vectorized 4-wide
// ---------------------------------------------------------------------------
__global__ void cast_bf16_kernel(const float* __restrict__ in,
                                 unsigned short* __restrict__ out, int n4) {
  int i = blockIdx.x * blockDim.x + threadIdx.x;
  int stride = gridDim.x * blockDim.x;
  for (; i < n4; i += stride) {
    float4 f = reinterpret_cast<const float4*>(in)[i];
    short4v o;
    o.x = (short)f2bf(f.x);
    o.y = (short)f2bf(f.y);
    o.z = (short)f2bf(f.z);
    o.w = (short)f2bf(f.w);
    reinterpret_cast<short4v*>(out)[i] = o;
  }
}

// ---------------------------------------------------------------------------
// GEMM: C[M,N] = A[M,K] · B[N,K]^T   (bf16 in, fp32 acc)
// 128x128 tile, BK=32, 4 waves (each 64x64 = 4x4 fragments of 16x16x32).
// MODE 0: bf16 store C[m*N+n] * scale
// MODE 2: fp32 store C[m*N+n] + bias[n]
// MODE 3: col<128 -> bf16 K store (stride 128); col>=128 -> bf16 V^T store
// ---------------------------------------------------------------------------
template <int MODE>
__global__ __launch_bounds__(256) void gemm_bt(
    const unsigned short* __restrict__ A, const unsigned short* __restrict__ B,
    void* __restrict__ Cout, int M, int N, int K, float scale,
    const float* __restrict__ bias, void* __restrict__ C2) {
  __shared__ unsigned short As[128 * 32] __attribute__((aligned(16)));
  __shared__ unsigned short Bs[128 * 32] __attribute__((aligned(16)));

  const int tid = threadIdx.x;
  const int lane = tid & 63;
  const int wave = tid >> 6;
  const int lr = lane & 15;
  const int lg = lane >> 4;
  const int bm = blockIdx.x * 128;
  const int bn = blockIdx.y * 128;
  const int wrow = (wave >> 1) * 64;
  const int wcol = (wave & 1) * 64;

  f32x4 acc[4][4] = {};

  const int c0 = tid;
  const int c1 = tid + 256;

  for (int k0 = 0; k0 < K; k0 += 32) {
    __syncthreads();
    gll16(A + (size_t)(bm + (c0 >> 2)) * K + k0 + (c0 & 3) * 8,
          (char*)As + wave * 1024);
    gll16(A + (size_t)(bm + (c1 >> 2)) * K + k0 + (c1 & 3) * 8,
          (char*)As + 4096 + wave * 1024);
    gll16(B + (size_t)(bn + (c0 >> 2)) * K + k0 + (c0 & 3) * 8,
          (char*)Bs + wave * 1024);
    gll16(B + (size_t)(bn + (c1 >> 2)) * K + k0 + (c1 & 3) * 8,
          (char*)Bs + 4096 + wave * 1024);
    __syncthreads();

    bf16x8 af[4], bfr[4];
#pragma unroll
    for (int mi = 0; mi < 4; mi++)
      af[mi] = *(const bf16x8*)&As[(wrow + mi * 16 + lr) * 32 + 8 * lg];
#pragma unroll
    for (int nj = 0; nj < 4; nj++)
      bfr[nj] = *(const bf16x8*)&Bs[(wcol + nj * 16 + lr) * 32 + 8 * lg];
#pragma unroll
    for (int mi = 0; mi < 4; mi++)
#pragma unroll
      for (int nj = 0; nj < 4; nj++)
        acc[mi][nj] = __builtin_amdgcn_mfma_f32_16x16x32_bf16(
            af[mi], bfr[nj], acc[mi][nj], 0, 0, 0);
  }

#pragma unroll
  for (int mi = 0; mi < 4; mi++)
#pragma unroll
    for (int nj = 0; nj < 4; nj++) {
      const int row = bm + wrow + mi * 16 + lg * 4;
      const int col = bn + wcol + nj * 16 + lr;
#pragma unroll
      for (int r = 0; r < 4; r++) {
        float v = acc[mi][nj][r] * scale;
        if constexpr (MODE == 0) {
          ((unsigned short*)Cout)[(size_t)(row + r) * N + col] = f2bf(v);
        } else if constexpr (MODE == 2) {
          ((float*)Cout)[(size_t)(row + r) * N + col] = v + bias[col];
        } else {  // MODE 3: fused K / V^T epilogue
          if (col < 128)
            ((unsigned short*)Cout)[(size_t)(row + r) * 128 + col] = f2bf(v);
          else
            ((unsigned short*)C2)[(size_t)(col - 128) * M + (row + r)] =
                f2bf(v);
        }
      }
    }
}

// ---------------------------------------------------------------------------
// Flash-style MQA attention, v3.
// Q: [B*L, 2048] bf16 pre-scaled by log2(e)/sqrt(dh)  (exp2-domain logits)
// K: [B*L, 128] bf16 ; VT: [128, B*L] bf16
// O: [B*L, 2048] bf16
// Block 256 = 4 waves sharing one (b,h); each wave owns 32 q-rows (mi=2).
// K[64x128] / VT[128x64] tiles staged in LDS per block (gll16, XOR-swizzled
// 16B chunks: lds chunk (row,c) holds global chunk (row, c^(row&7))).
// grid: (L/128, B*H) = (16, 32)
// ---------------------------------------------------------------------------
__global__ __launch_bounds__(256) void mqa_attn(
    const unsigned short* __restrict__ Q, const unsigned short* __restrict__ Kb,
    const unsigned short* __restrict__ VT, unsigned short* __restrict__ Ob) {
  __shared__ unsigned short Ks[64 * 128] __attribute__((aligned(16)));
  __shared__ unsigned short Vs[128 * 64] __attribute__((aligned(16)));
  // per-wave, per-mi P tile: 16 x 64, row stride 72 shorts (144B)
  __shared__ unsigned short ldsP[4][2][16][72] __attribute__((aligned(16)));

  const int tid = threadIdx.x;
  const int lane = tid & 63;
  const int wave = tid >> 6;
  const int lr = lane & 15;
  const int lg = lane >> 4;
  const int bh = blockIdx.y;
  const int b = bh >> 4;
  const int h = bh & 15;
  const int q0 = blockIdx.x * 128 + wave * 32;

  const unsigned short* Qb = Q + ((size_t)(b * 2048 + q0)) * 2048 + h * 128;
  const unsigned short* Kbase = Kb + (size_t)b * 2048 * 128;
  const unsigned short* VTb = VT + (size_t)b * 2048;

  // Q fragments: A[m=q][k=d], lane: m=lr, k=8*lg+i
  bf16x8 qf[2][4];
#pragma unroll
  for (int mi = 0; mi < 2; mi++)
#pragma unroll
    for (int ks = 0; ks < 4; ks++)
      qf[mi][ks] =
          *(const bf16x8*)&Qb[(size_t)(mi * 16 + lr) * 2048 + ks * 32 + 8 * lg];

  f32x4 oacc[2][8] = {};
  float mrun[2][4], lrun[2][4];
#pragma unroll
  for (int mi = 0; mi < 2; mi++)
#pragma unroll
    for (int r = 0; r < 4; r++) {
      mrun[mi][r] = -1e30f;
      lrun[mi][r] = 0.0f;
    }

  // precomputed swizzled staging source offsets (16B chunks)
  // K tile: 1024 chunks, 16/row; V tile: 1024 chunks, 8/row
  int kro[4], kco[4], vro[4], vco[4];
#pragma unroll
  for (int t = 0; t < 4; t++) {
    int c = t * 256 + tid;
    kro[t] = c >> 4;
    kco[t] = ((c & 15) ^ (kro[t] & 7)) * 8;
    vro[t] = c >> 3;
    vco[t] = ((c & 7) ^ (vro[t] & 7)) * 8;
  }

  for (int kv0 = 0; kv0 < 2048; kv0 += 64) {
    __syncthreads();  // all reads of previous tiles complete
#pragma unroll
    for (int t = 0; t < 4; t++) {
      gll16(Kbase + (size_t)(kv0 + kro[t]) * 128 + kco[t],
            (char*)Ks + t * 4096 + wave * 1024);
      gll16(VTb + (size_t)vro[t] * 4096 + kv0 + vco[t],
            (char*)Vs + t * 4096 + wave * 1024);
    }
    __syncthreads();  // vmcnt drain emitted by compiler before s_barrier

    // S = Q·K^T: s[mi][nj], rows lg*4+r, cols kv0 + nj*16 + lr
    f32x4 s[2][4];
#pragma unroll
    for (int nj = 0; nj < 4; nj++) {
      const int krow = nj * 16 + lr;
      bf16x8 kf[4];
#pragma unroll
      for (int ks = 0; ks < 4; ks++) {
        const int lc = (ks * 4 + lg) ^ (krow & 7);
        kf[ks] = *(const bf16x8*)&Ks[krow * 128 + lc * 8];
      }
#pragma unroll
      for (int mi = 0; mi < 2; mi++) {
        f32x4 z = {0.f, 0.f, 0.f, 0.f};
#pragma unroll
        for (int ks = 0; ks < 4; ks++)
          z = __builtin_amdgcn_mfma_f32_16x16x32_bf16(qf[mi][ks], kf[ks], z, 0,
                                                      0, 0);
        s[mi][nj] = z;
      }
    }

    // online softmax (log2 domain), defer-rescale THR=8
#pragma unroll
    for (int mi = 0; mi < 2; mi++) {
      float tm[4];
      bool ok = true;
#pragma unroll
      for (int r = 0; r < 4; r++) {
        float t = fmaxf(fmaxf(s[mi][0][r], s[mi][1][r]),
                        fmaxf(s[mi][2][r], s[mi][3][r]));
        t = fmaxf(t, __shfl_xor(t, 1));
        t = fmaxf(t, __shfl_xor(t, 2));
        t = fmaxf(t, __shfl_xor(t, 4));
        t = fmaxf(t, __shfl_xor(t, 8));
        tm[r] = t;
        ok = ok && (t <= mrun[mi][r] + 8.0f);
      }
      if (!__all(ok)) {  // rare after first tile
#pragma unroll
        for (int r = 0; r < 4; r++) {
          float mnew = fmaxf(mrun[mi][r], tm[r]);
          float sc = exp2f(mrun[mi][r] - mnew);
          mrun[mi][r] = mnew;
          lrun[mi][r] *= sc;
#pragma unroll
          for (int dt = 0; dt < 8; dt++) oacc[mi][dt][r] *= sc;
        }
      }
#pragma unroll
      for (int r = 0; r < 4; r++) {
        float p0 = exp2f(s[mi][0][r] - mrun[mi][r]);
        float p1 = exp2f(s[mi][1][r] - mrun[mi][r]);
        float p2 = exp2f(s[mi][2][r] - mrun[mi][r]);
        float p3 = exp2f(s[mi][3][r] - mrun[mi][r]);
        float ps = (p0 + p1) + (p2 + p3);
        ps += __shfl_xor(ps, 1);
        ps += __shfl_xor(ps, 2);
        ps += __shfl_xor(ps, 4);
        ps += __shfl_xor(ps, 8);
        lrun[mi][r] += ps;
        ldsP[wave][mi][lg * 4 + r][lr] = f2bf(p0);
        ldsP[wave][mi][lg * 4 + r][16 + lr] = f2bf(p1);
        ldsP[wave][mi][lg * 4 + r][32 + lr] = f2bf(p2);
        ldsP[wave][mi][lg * 4 + r][48 + lr] = f2bf(p3);
      }
    }

    // PV: V^T frags hoisted (shared by both mi), swizzled LDS read
    bf16x8 vf[8][2];
#pragma unroll
    for (int dt = 0; dt < 8; dt++) {
      const int vrow = dt * 16 + lr;
#pragma unroll
      for (int hf = 0; hf < 2; hf++) {
        const int lc = (hf * 4 + lg) ^ (vrow & 7);
        vf[dt][hf] = *(const bf16x8*)&Vs[vrow * 64 + lc * 8];
      }
    }
#pragma unroll
    for (int mi = 0; mi < 2; mi++) {
      bf16x8 pa0 = *(const bf16x8*)&ldsP[wave][mi][lr][8 * lg];
      bf16x8 pa1 = *(const bf16x8*)&ldsP[wave][mi][lr][32 + 8 * lg];
#pragma unroll
      for (int dt = 0; dt < 8; dt++) {
        oacc[mi][dt] = __builtin_amdgcn_mfma_f32_16x16x32_bf16(
            pa0, vf[dt][0], oacc[mi][dt], 0, 0, 0);
        oacc[mi][dt] = __builtin_amdgcn_mfma_f32_16x16x32_bf16(
            pa1, vf[dt][1], oacc[mi][dt], 0, 0, 0);
      }
    }
  }

#pragma unroll
  for (int mi = 0; mi < 2; mi++)
#pragma unroll
    for (int r = 0; r < 4; r++) {
      float inv = 1.0f / lrun[mi][r];
      size_t row = (size_t)(b * 2048 + q0 + mi * 16 + lg * 4 + r);
#pragma unroll
      for (int dt = 0; dt < 8; dt++)
        Ob[row * 2048 + h * 128 + dt * 16 + lr] = f2bf(oacc[mi][dt][r] * inv);
    }
}

// ---------------------------------------------------------------------------
extern "C" void kernel_launch(void* const* d_in, const int* in_sizes, int n_in,
                              void* d_out, int out_size, void* d_ws,
                              size_t ws_size, hipStream_t stream) {
  const float* x = (const float*)d_in[0];
  const float* Wq = (const float*)d_in[1];
  const float* Wk = (const float*)d_in[2];
  const float* Wv = (const float*)d_in[3];
  const float* Wo = (const float*)d_in[4];
  const float* bo = (const float*)d_in[5];

  const int Bb = 2, Lq = 2048, D = 2048, DH = 128;
  const int M = Bb * Lq;  // 4096

  char* ws = (char*)d_ws;
  size_t off = 0;
  auto alloc = [&](size_t bytes) {
    void* p = ws + off;
    off += (bytes + 255) & ~size_t(255);
    return p;
  };
  unsigned short* x_bf = (unsigned short*)alloc((size_t)M * D * 2);
  unsigned short* Wq_bf = (unsigned short*)alloc((size_t)D * D * 2);
  unsigned short* Wkv_bf = (unsigned short*)alloc((size_t)2 * DH * D * 2);
  unsigned short* Wo_bf = (unsigned short*)alloc((size_t)D * D * 2);
  unsigned short* Qbuf = (unsigned short*)alloc((size_t)M * D * 2);
  unsigned short* Kbuf = (unsigned short*)alloc((size_t)M * DH * 2);
  unsigned short* VTbuf = (unsigned short*)alloc((size_t)DH * M * 2);
  unsigned short* AObuf = (unsigned short*)alloc((size_t)M * D * 2);

  auto cast = [&](const float* in, unsigned short* outp, int n) {
    int n4 = n >> 2;
    int grid = (n4 + 255) / 256;
    if (grid > 2048) grid = 2048;
    cast_bf16_kernel<<<grid, 256, 0, stream>>>(in, outp, n4);
  };
  cast(x, x_bf, M * D);
  cast(Wq, Wq_bf, D * D);
  cast(Wk, Wkv_bf, DH * D);                   // rows 0..127 of fused KV
  cast(Wv, Wkv_bf + (size_t)DH * D, DH * D);  // rows 128..255
  cast(Wo, Wo_bf, D * D);

  // Q = x·Wq^T scaled by log2(e)/sqrt(dh): logits land in exp2 domain
  gemm_bt<0><<<dim3(M / 128, D / 128), 256, 0, stream>>>(
      x_bf, Wq_bf, Qbuf, M, D, D, 0.12752041986f, nullptr, nullptr);
  // K and V^T in one GEMM (N=256)
  gemm_bt<3><<<dim3(M / 128, 2), 256, 0, stream>>>(
      x_bf, Wkv_bf, Kbuf, M, 2 * DH, D, 1.0f, nullptr, VTbuf);
  // attention
  mqa_attn<<<dim3(Lq / 128, Bb * 16), 256, 0, stream>>>(Qbuf, Kbuf, VTbuf,
                                                        AObuf);
  // out = AO·Wo^T + bo  (fp32 output)
  gemm_bt<2><<<dim3(M / 128, D / 128), 256, 0, stream>>>(
      AObuf, Wo_bf, d_out, M, D, D, 1.0f, bo, nullptr);
}

// Round 4
// 325.782 us; speedup vs baseline: 1.9596x; 1.2086x over previous
//
#include <hip/hip_runtime.h>

// ---------------------------------------------------------------------------
// MQA forward: out = OutProj( MHA( x·Wq^T, x·Wk^T, x·Wv^T ) )
// B=2, L=2048, D=2048, H=16, dh=128 (MQA: K/V shared across heads)
// R4: attn rewritten on swapped-QK^T 32x32 MFMA with in-register softmax
// (T12-style): lane owns q-row; no P LDS round-trip; 1 shfl per reduction.
// K/V LDS staging with XOR swizzle kept from R3.
// ---------------------------------------------------------------------------

typedef __attribute__((ext_vector_type(8))) short bf16x8;
typedef __attribute__((ext_vector_type(4))) short short4v;
typedef __attribute__((ext_vector_type(4))) float f32x4;
typedef __attribute__((ext_vector_type(16))) float f32x16;
typedef __attribute__((ext_vector_type(4))) int int4v;

__device__ __forceinline__ unsigned short f2bf(float f) {
  unsigned int u = __builtin_bit_cast(unsigned int, f);
  u += 0x7fffu + ((u >> 16) & 1u);  // RNE (finite inputs only)
  return (unsigned short)(u >> 16);
}

__device__ __forceinline__ unsigned int pk2bf(float lo, float hi) {
  return (unsigned int)f2bf(lo) | ((unsigned int)f2bf(hi) << 16);
}

typedef __attribute__((address_space(1))) void gvoid_t;
typedef __attribute__((address_space(3))) void lvoid_t;

__device__ __forceinline__ void gll16(const void* g, void* l) {
  __builtin_amdgcn_global_load_lds((gvoid_t*)g, (lvoid_t*)l, 16, 0, 0);
}

// ---------------------------------------------------------------------------
// fp32 -> bf16 cast, vectorized 4-wide
// ---------------------------------------------------------------------------
__global__ void cast_bf16_kernel(const float* __restrict__ in,
                                 unsigned short* __restrict__ out, int n4) {
  int i = blockIdx.x * blockDim.x + threadIdx.x;
  int stride = gridDim.x * blockDim.x;
  for (; i < n4; i += stride) {
    float4 f = reinterpret_cast<const float4*>(in)[i];
    short4v o;
    o.x = (short)f2bf(f.x);
    o.y = (short)f2bf(f.y);
    o.z = (short)f2bf(f.z);
    o.w = (short)f2bf(f.w);
    reinterpret_cast<short4v*>(out)[i] = o;
  }
}

// ---------------------------------------------------------------------------
// GEMM: C[M,N] = A[M,K] · B[N,K]^T   (bf16 in, fp32 acc)  — unchanged (R3)
// ---------------------------------------------------------------------------
template <int MODE>
__global__ __launch_bounds__(256) void gemm_bt(
    const unsigned short* __restrict__ A, const unsigned short* __restrict__ B,
    void* __restrict__ Cout, int M, int N, int K, float scale,
    const float* __restrict__ bias, void* __restrict__ C2) {
  __shared__ unsigned short As[128 * 32] __attribute__((aligned(16)));
  __shared__ unsigned short Bs[128 * 32] __attribute__((aligned(16)));

  const int tid = threadIdx.x;
  const int lane = tid & 63;
  const int wave = tid >> 6;
  const int lr = lane & 15;
  const int lg = lane >> 4;
  const int bm = blockIdx.x * 128;
  const int bn = blockIdx.y * 128;
  const int wrow = (wave >> 1) * 64;
  const int wcol = (wave & 1) * 64;

  f32x4 acc[4][4] = {};

  const int c0 = tid;
  const int c1 = tid + 256;

  for (int k0 = 0; k0 < K; k0 += 32) {
    __syncthreads();
    gll16(A + (size_t)(bm + (c0 >> 2)) * K + k0 + (c0 & 3) * 8,
          (char*)As + wave * 1024);
    gll16(A + (size_t)(bm + (c1 >> 2)) * K + k0 + (c1 & 3) * 8,
          (char*)As + 4096 + wave * 1024);
    gll16(B + (size_t)(bn + (c0 >> 2)) * K + k0 + (c0 & 3) * 8,
          (char*)Bs + wave * 1024);
    gll16(B + (size_t)(bn + (c1 >> 2)) * K + k0 + (c1 & 3) * 8,
          (char*)Bs + 4096 + wave * 1024);
    __syncthreads();

    bf16x8 af[4], bfr[4];
#pragma unroll
    for (int mi = 0; mi < 4; mi++)
      af[mi] = *(const bf16x8*)&As[(wrow + mi * 16 + lr) * 32 + 8 * lg];
#pragma unroll
    for (int nj = 0; nj < 4; nj++)
      bfr[nj] = *(const bf16x8*)&Bs[(wcol + nj * 16 + lr) * 32 + 8 * lg];
#pragma unroll
    for (int mi = 0; mi < 4; mi++)
#pragma unroll
      for (int nj = 0; nj < 4; nj++)
        acc[mi][nj] = __builtin_amdgcn_mfma_f32_16x16x32_bf16(
            af[mi], bfr[nj], acc[mi][nj], 0, 0, 0);
  }

#pragma unroll
  for (int mi = 0; mi < 4; mi++)
#pragma unroll
    for (int nj = 0; nj < 4; nj++) {
      const int row = bm + wrow + mi * 16 + lg * 4;
      const int col = bn + wcol + nj * 16 + lr;
#pragma unroll
      for (int r = 0; r < 4; r++) {
        float v = acc[mi][nj][r] * scale;
        if constexpr (MODE == 0) {
          ((unsigned short*)Cout)[(size_t)(row + r) * N + col] = f2bf(v);
        } else if constexpr (MODE == 2) {
          ((float*)Cout)[(size_t)(row + r) * N + col] = v + bias[col];
        } else {  // MODE 3: fused K / V^T epilogue
          if (col < 128)
            ((unsigned short*)Cout)[(size_t)(row + r) * 128 + col] = f2bf(v);
          else
            ((unsigned short*)C2)[(size_t)(col - 128) * M + (row + r)] =
                f2bf(v);
        }
      }
    }
}

// ---------------------------------------------------------------------------
// Flash-style MQA attention, v4: swapped QK^T (32x32 MFMA), in-reg softmax.
// Q: [B*L, 2048] bf16 pre-scaled by log2(e)/sqrt(dh)  (exp2-domain logits)
// K: [B*L, 128] bf16 ; VT: [128, B*L] bf16
// O: [B*L, 2048] bf16
// Block 256 = 4 waves sharing one (b,h); each wave owns 32 q-rows.
// ST = mfma(A=K, B=Q): lane q = lane&31; kv row of reg r = (r&3)+8*(r>>2)+4*hi.
// P -> PV A-frags in-register: pack pairs + shfl_xor(·,32) + cndmask.
// PV = mfma(A=P, B=V): C row q=(r&3)+8*(r>>2)+4*hi, col d = dt*32 + (lane&31).
// grid: (L/128, B*H) = (16, 32)
// ---------------------------------------------------------------------------
__global__ __launch_bounds__(256) void mqa_attn(
    const unsigned short* __restrict__ Q, const unsigned short* __restrict__ Kb,
    const unsigned short* __restrict__ VT, unsigned short* __restrict__ Ob) {
  __shared__ unsigned short Ks[64 * 128] __attribute__((aligned(16)));
  __shared__ unsigned short Vs[128 * 64] __attribute__((aligned(16)));

  const int tid = threadIdx.x;
  const int lane = tid & 63;
  const int wave = tid >> 6;
  const int l31 = lane & 31;
  const int hi = lane >> 5;
  const int bh = blockIdx.y;
  const int b = bh >> 4;
  const int h = bh & 15;
  const int q0 = blockIdx.x * 128 + wave * 32;

  const unsigned short* Qb = Q + ((size_t)(b * 2048 + q0)) * 2048 + h * 128;
  const unsigned short* Kbase = Kb + (size_t)b * 2048 * 128;
  const unsigned short* VTb = VT + (size_t)b * 2048;

  // Q B-frags: q = l31, d = 16*ks + 8*hi + i   (8 k-steps over dh=128)
  bf16x8 qf[8];
#pragma unroll
  for (int ks = 0; ks < 8; ks++)
    qf[ks] = *(const bf16x8*)&Qb[(size_t)l31 * 2048 + ks * 16 + hi * 8];

  f32x16 oacc[4] = {};  // O[q][d]: col d = dt*32+l31, row q = (r&3)+8*(r>>2)+4hi
  float mrun = -1e30f, lrun = 0.0f;

  // staging source offsets (16B chunks), XOR-swizzled (write side)
  int kro[4], kco[4], vro[4], vco[4];
#pragma unroll
  for (int t = 0; t < 4; t++) {
    int c = t * 256 + tid;
    kro[t] = c >> 4;
    kco[t] = ((c & 15) ^ (kro[t] & 7)) * 8;
    vro[t] = c >> 3;
    vco[t] = ((c & 7) ^ (vro[t] & 7)) * 8;
  }

  for (int kv0 = 0; kv0 < 2048; kv0 += 64) {
    __syncthreads();  // previous tile fully consumed
#pragma unroll
    for (int t = 0; t < 4; t++) {
      gll16(Kbase + (size_t)(kv0 + kro[t]) * 128 + kco[t],
            (char*)Ks + t * 4096 + wave * 1024);
      gll16(VTb + (size_t)vro[t] * 4096 + kv0 + vco[t],
            (char*)Vs + t * 4096 + wave * 1024);
    }
    __syncthreads();  // vmcnt drain before barrier (compiler-emitted)

    // ST[sub][r] = S[kv = sub*32 + (r&3)+8*(r>>2)+4*hi][q = l31]
    f32x16 st[2];
#pragma unroll
    for (int sub = 0; sub < 2; sub++) {
      f32x16 z = {};
      const int krow = sub * 32 + l31;
#pragma unroll
      for (int ks = 0; ks < 8; ks++) {
        const int lc = (2 * ks + hi) ^ (krow & 7);
        bf16x8 kf = *(const bf16x8*)&Ks[krow * 128 + lc * 8];
        z = __builtin_amdgcn_mfma_f32_32x32x16_bf16(kf, qf[ks], z, 0, 0, 0);
      }
      st[sub] = z;
    }

    // ---- in-register online softmax (q = l31 per lane, log2 domain) ----
    float tm = st[0][0];
#pragma unroll
    for (int r = 1; r < 16; r++) tm = fmaxf(tm, st[0][r]);
#pragma unroll
    for (int r = 0; r < 16; r++) tm = fmaxf(tm, st[1][r]);
    tm = fmaxf(tm, __shfl_xor(tm, 32));  // merge partner half of the row

    if (!__all(tm <= mrun + 8.0f)) {  // defer-rescale THR=8 (log2)
      float mnew = fmaxf(mrun, tm);
      float sc = exp2f(mrun - mnew);
      mrun = mnew;
      lrun *= sc;
#pragma unroll
      for (int r = 0; r < 16; r++) {
        float scr = __shfl(sc, (r & 3) + 8 * (r >> 2) + 4 * hi);
#pragma unroll
        for (int dt = 0; dt < 4; dt++) oacc[dt][r] *= scr;
      }
    }

    float p[2][16];
    float ps = 0.0f;
#pragma unroll
    for (int sub = 0; sub < 2; sub++)
#pragma unroll
      for (int r = 0; r < 16; r++) {
        p[sub][r] = exp2f(st[sub][r] - mrun);
        ps += p[sub][r];
      }
    ps += __shfl_xor(ps, 32);
    lrun += ps;

    // ---- pack P -> PV A-frags (kv k-steps ks2 = sub*2 + h2) ----
    // own groups per h2: a* = kv 16h2+4hi+{0..3}, b* = kv 16h2+8+4hi+{0..3}
    // frag needs kv 16h2+8hi+{0..7}: own half + partner half via shfl_xor(32)
    bf16x8 paw[4];
#pragma unroll
    for (int sub = 0; sub < 2; sub++)
#pragma unroll
      for (int h2 = 0; h2 < 2; h2++) {
        unsigned int a0 = pk2bf(p[sub][8 * h2 + 0], p[sub][8 * h2 + 1]);
        unsigned int a1 = pk2bf(p[sub][8 * h2 + 2], p[sub][8 * h2 + 3]);
        unsigned int b0 = pk2bf(p[sub][8 * h2 + 4], p[sub][8 * h2 + 5]);
        unsigned int b1 = pk2bf(p[sub][8 * h2 + 6], p[sub][8 * h2 + 7]);
        unsigned int s0 = hi ? a0 : b0;  // what partner needs from me
        unsigned int s1 = hi ? a1 : b1;
        unsigned int r0 = (unsigned int)__shfl_xor((int)s0, 32);
        unsigned int r1 = (unsigned int)__shfl_xor((int)s1, 32);
        int4v w;
        w.x = (int)(hi ? r0 : a0);
        w.y = (int)(hi ? r1 : a1);
        w.z = (int)(hi ? b0 : r0);
        w.w = (int)(hi ? b1 : r1);
        paw[sub * 2 + h2] = __builtin_bit_cast(bf16x8, w);
      }

    // ---- PV: O[q][dt*32+l31] += P · V ----
#pragma unroll
    for (int dt = 0; dt < 4; dt++) {
      const int vrow = dt * 32 + l31;
      f32x16 z = oacc[dt];
#pragma unroll
      for (int ks2 = 0; ks2 < 4; ks2++) {
        const int lc = (2 * ks2 + hi) ^ (vrow & 7);
        bf16x8 vfr = *(const bf16x8*)&Vs[vrow * 64 + lc * 8];
        z = __builtin_amdgcn_mfma_f32_32x32x16_bf16(paw[ks2], vfr, z, 0, 0, 0);
      }
      oacc[dt] = z;
    }
  }

  // epilogue: normalize by row-sum (broadcast lrun from lane q) and store
  float inv = 1.0f / lrun;
#pragma unroll
  for (int r = 0; r < 16; r++) {
    const int qrow = (r & 3) + 8 * (r >> 2) + 4 * hi;
    float invr = __shfl(inv, qrow);
    size_t row = (size_t)(b * 2048 + q0 + qrow);
#pragma unroll
    for (int dt = 0; dt < 4; dt++)
      Ob[row * 2048 + h * 128 + dt * 32 + l31] = f2bf(oacc[dt][r] * invr);
  }
}

// ---------------------------------------------------------------------------
extern "C" void kernel_launch(void* const* d_in, const int* in_sizes, int n_in,
                              void* d_out, int out_size, void* d_ws,
                              size_t ws_size, hipStream_t stream) {
  const float* x = (const float*)d_in[0];
  const float* Wq = (const float*)d_in[1];
  const float* Wk = (const float*)d_in[2];
  const float* Wv = (const float*)d_in[3];
  const float* Wo = (const float*)d_in[4];
  const float* bo = (const float*)d_in[5];

  const int Bb = 2, Lq = 2048, D = 2048, DH = 128;
  const int M = Bb * Lq;  // 4096

  char* ws = (char*)d_ws;
  size_t off = 0;
  auto alloc = [&](size_t bytes) {
    void* p = ws + off;
    off += (bytes + 255) & ~size_t(255);
    return p;
  };
  unsigned short* x_bf = (unsigned short*)alloc((size_t)M * D * 2);
  unsigned short* Wq_bf = (unsigned short*)alloc((size_t)D * D * 2);
  unsigned short* Wkv_bf = (unsigned short*)alloc((size_t)2 * DH * D * 2);
  unsigned short* Wo_bf = (unsigned short*)alloc((size_t)D * D * 2);
  unsigned short* Qbuf = (unsigned short*)alloc((size_t)M * D * 2);
  unsigned short* Kbuf = (unsigned short*)alloc((size_t)M * DH * 2);
  unsigned short* VTbuf = (unsigned short*)alloc((size_t)DH * M * 2);
  unsigned short* AObuf = (unsigned short*)alloc((size_t)M * D * 2);

  auto cast = [&](const float* in, unsigned short* outp, int n) {
    int n4 = n >> 2;
    int grid = (n4 + 255) / 256;
    if (grid > 2048) grid = 2048;
    cast_bf16_kernel<<<grid, 256, 0, stream>>>(in, outp, n4);
  };
  cast(x, x_bf, M * D);
  cast(Wq, Wq_bf, D * D);
  cast(Wk, Wkv_bf, DH * D);                   // rows 0..127 of fused KV
  cast(Wv, Wkv_bf + (size_t)DH * D, DH * D);  // rows 128..255
  cast(Wo, Wo_bf, D * D);

  // Q = x·Wq^T scaled by log2(e)/sqrt(dh): logits land in exp2 domain
  gemm_bt<0><<<dim3(M / 128, D / 128), 256, 0, stream>>>(
      x_bf, Wq_bf, Qbuf, M, D, D, 0.12752041986f, nullptr, nullptr);
  // K and V^T in one GEMM (N=256)
  gemm_bt<3><<<dim3(M / 128, 2), 256, 0, stream>>>(
      x_bf, Wkv_bf, Kbuf, M, 2 * DH, D, 1.0f, nullptr, VTbuf);
  // attention
  mqa_attn<<<dim3(Lq / 128, Bb * 16), 256, 0, stream>>>(Qbuf, Kbuf, VTbuf,
                                                        AObuf);
  // out = AO·Wo^T + bo  (fp32 output)
  gemm_bt<2><<<dim3(M / 128, D / 128), 256, 0, stream>>>(
      AObuf, Wo_bf, d_out, M, D, D, 1.0f, bo, nullptr);
}

// Round 6
// 304.898 us; speedup vs baseline: 2.0938x; 1.0685x over previous
//
#include <hip/hip_runtime.h>

// ---------------------------------------------------------------------------
// MQA forward: out = OutProj( MHA( x·Wq^T, x·Wk^T, x·Wv^T ) )
// B=2, L=2048, D=2048, H=16, dh=128 (MQA: K/V shared across heads)
// R6: R5 with the V-tile LDS stride bug fixed (Vs superrow stride is 16
// chunks = 256B = 128 shorts; R5 declared/read at 512B -> read unwritten
// LDS -> NaN). K/V swizzles, 2-phase double-buffer, in-reg softmax kept.
// ---------------------------------------------------------------------------

typedef __attribute__((ext_vector_type(8))) short bf16x8;
typedef __attribute__((ext_vector_type(4))) short short4v;
typedef __attribute__((ext_vector_type(4))) float f32x4;
typedef __attribute__((ext_vector_type(16))) float f32x16;
typedef __attribute__((ext_vector_type(4))) int int4v;

__device__ __forceinline__ unsigned short f2bf(float f) {
  unsigned int u = __builtin_bit_cast(unsigned int, f);
  u += 0x7fffu + ((u >> 16) & 1u);  // RNE (finite inputs only)
  return (unsigned short)(u >> 16);
}

__device__ __forceinline__ unsigned int pk2bf(float lo, float hi) {
  return (unsigned int)f2bf(lo) | ((unsigned int)f2bf(hi) << 16);
}

typedef __attribute__((address_space(1))) void gvoid_t;
typedef __attribute__((address_space(3))) void lvoid_t;

__device__ __forceinline__ void gll16(const void* g, void* l) {
  __builtin_amdgcn_global_load_lds((gvoid_t*)g, (lvoid_t*)l, 16, 0, 0);
}

// ---------------------------------------------------------------------------
// fp32 -> bf16 cast, vectorized 4-wide
// ---------------------------------------------------------------------------
__global__ void cast_bf16_kernel(const float* __restrict__ in,
                                 unsigned short* __restrict__ out, int n4) {
  int i = blockIdx.x * blockDim.x + threadIdx.x;
  int stride = gridDim.x * blockDim.x;
  for (; i < n4; i += stride) {
    float4 f = reinterpret_cast<const float4*>(in)[i];
    short4v o;
    o.x = (short)f2bf(f.x);
    o.y = (short)f2bf(f.y);
    o.z = (short)f2bf(f.z);
    o.w = (short)f2bf(f.w);
    reinterpret_cast<short4v*>(out)[i] = o;
  }
}

// ---------------------------------------------------------------------------
// GEMM: C[M,N] = A[M,K] · B[N,K]^T   (bf16 in, fp32 acc)  — unchanged
// ---------------------------------------------------------------------------
template <int MODE>
__global__ __launch_bounds__(256) void gemm_bt(
    const unsigned short* __restrict__ A, const unsigned short* __restrict__ B,
    void* __restrict__ Cout, int M, int N, int K, float scale,
    const float* __restrict__ bias, void* __restrict__ C2) {
  __shared__ unsigned short As[128 * 32] __attribute__((aligned(16)));
  __shared__ unsigned short Bs[128 * 32] __attribute__((aligned(16)));

  const int tid = threadIdx.x;
  const int lane = tid & 63;
  const int wave = tid >> 6;
  const int lr = lane & 15;
  const int lg = lane >> 4;
  const int bm = blockIdx.x * 128;
  const int bn = blockIdx.y * 128;
  const int wrow = (wave >> 1) * 64;
  const int wcol = (wave & 1) * 64;

  f32x4 acc[4][4] = {};

  const int c0 = tid;
  const int c1 = tid + 256;

  for (int k0 = 0; k0 < K; k0 += 32) {
    __syncthreads();
    gll16(A + (size_t)(bm + (c0 >> 2)) * K + k0 + (c0 & 3) * 8,
          (char*)As + wave * 1024);
    gll16(A + (size_t)(bm + (c1 >> 2)) * K + k0 + (c1 & 3) * 8,
          (char*)As + 4096 + wave * 1024);
    gll16(B + (size_t)(bn + (c0 >> 2)) * K + k0 + (c0 & 3) * 8,
          (char*)Bs + wave * 1024);
    gll16(B + (size_t)(bn + (c1 >> 2)) * K + k0 + (c1 & 3) * 8,
          (char*)Bs + 4096 + wave * 1024);
    __syncthreads();

    bf16x8 af[4], bfr[4];
#pragma unroll
    for (int mi = 0; mi < 4; mi++)
      af[mi] = *(const bf16x8*)&As[(wrow + mi * 16 + lr) * 32 + 8 * lg];
#pragma unroll
    for (int nj = 0; nj < 4; nj++)
      bfr[nj] = *(const bf16x8*)&Bs[(wcol + nj * 16 + lr) * 32 + 8 * lg];
#pragma unroll
    for (int mi = 0; mi < 4; mi++)
#pragma unroll
      for (int nj = 0; nj < 4; nj++)
        acc[mi][nj] = __builtin_amdgcn_mfma_f32_16x16x32_bf16(
            af[mi], bfr[nj], acc[mi][nj], 0, 0, 0);
  }

#pragma unroll
  for (int mi = 0; mi < 4; mi++)
#pragma unroll
    for (int nj = 0; nj < 4; nj++) {
      const int row = bm + wrow + mi * 16 + lg * 4;
      const int col = bn + wcol + nj * 16 + lr;
#pragma unroll
      for (int r = 0; r < 4; r++) {
        float v = acc[mi][nj][r] * scale;
        if constexpr (MODE == 0) {
          ((unsigned short*)Cout)[(size_t)(row + r) * N + col] = f2bf(v);
        } else if constexpr (MODE == 2) {
          ((float*)Cout)[(size_t)(row + r) * N + col] = v + bias[col];
        } else {  // MODE 3: fused K / V^T epilogue
          if (col < 128)
            ((unsigned short*)Cout)[(size_t)(row + r) * 128 + col] = f2bf(v);
          else
            ((unsigned short*)C2)[(size_t)(col - 128) * M + (row + r)] =
                f2bf(v);
        }
      }
    }
}

// ---------------------------------------------------------------------------
// Flash-style MQA attention, v6 (v5 + Vs stride fix).
// Q: [B*L, 2048] bf16 pre-scaled by log2(e)/sqrt(dh)  (exp2-domain logits)
// K: [B*L, 128] bf16 ; VT: [128, B*L] bf16
// O: [B*L, 2048] bf16
// Block 256 = 4 waves sharing one (b,h); each wave owns 32 q-rows.
// K tile LDS: [64 rows][16 chunks], chunk pos = c ^ (row&15)       (uniform)
// V tile LDS: [64 superrows(d/2)][16 slots], slot = (c+8*(d&1)) ^ ((d>>1)&15)
//   superrow stride = 16 chunks * 16B = 256B = 128 shorts (THE R5 FIX)
// Double-buffered; stage next tile at iter top, vmcnt(0)+barrier at iter end.
// grid: (L/128, B*H) = (16, 32)
// ---------------------------------------------------------------------------
__global__ __launch_bounds__(256) void mqa_attn(
    const unsigned short* __restrict__ Q, const unsigned short* __restrict__ Kb,
    const unsigned short* __restrict__ VT, unsigned short* __restrict__ Ob) {
  __shared__ unsigned short Ks[2][64 * 128] __attribute__((aligned(16)));
  __shared__ unsigned short Vs[2][64 * 128] __attribute__((aligned(16)));

  const int tid = threadIdx.x;
  const int lane = tid & 63;
  const int wave = tid >> 6;
  const int l31 = lane & 31;
  const int hi = lane >> 5;
  const int bh = blockIdx.y;
  const int b = bh >> 4;
  const int h = bh & 15;
  const int q0 = blockIdx.x * 128 + wave * 32;

  const unsigned short* Qb = Q + ((size_t)(b * 2048 + q0)) * 2048 + h * 128;
  const unsigned short* Kbase = Kb + (size_t)b * 2048 * 128;
  const unsigned short* VTb = VT + (size_t)b * 2048;

  // Q B-frags: q = l31, d = 16*ks + 8*hi + i   (8 k-steps over dh=128)
  bf16x8 qf[8];
#pragma unroll
  for (int ks = 0; ks < 8; ks++)
    qf[ks] = *(const bf16x8*)&Qb[(size_t)l31 * 2048 + ks * 16 + hi * 8];

  f32x16 oacc[4] = {};  // O[q][d]: col d = dt*32+l31, row q=(r&3)+8(r>>2)+4hi
  float mrun = -1e30f, lrun = 0.0f;

  // staging source offsets (elements), inverse of the LDS placement
  int koff[4], voff[4];
#pragma unroll
  for (int t = 0; t < 4; t++) {
    int ci = t * 256 + tid;           // linear 16B chunk id 0..1023
    int krow = ci >> 4;
    int kc = (ci ^ krow) & 15;        // global chunk col = pos ^ (row&15)
    koff[t] = krow * 128 + kc * 8;
    int s = ci >> 4;                  // V superrow
    int u = (ci ^ s) & 15;            // (slot) ^ (s&15)
    voff[t] = (2 * s + (u >> 3)) * 4096 + (u & 7) * 8;
  }

  auto stage = [&](int kv0, int bsel) {
#pragma unroll
    for (int t = 0; t < 4; t++) {
      gll16(Kbase + (size_t)kv0 * 128 + koff[t],
            (char*)&Ks[bsel][0] + t * 4096 + wave * 1024);
      gll16(VTb + kv0 + voff[t],
            (char*)&Vs[bsel][0] + t * 4096 + wave * 1024);
    }
  };

  // prologue: tile 0 into buffer 0
  stage(0, 0);
  asm volatile("s_waitcnt vmcnt(0)" ::: "memory");
  __builtin_amdgcn_sched_barrier(0);
  __builtin_amdgcn_s_barrier();

  for (int t = 0; t < 32; t++) {
    const int cur = t & 1;
    stage(((t + 1) & 31) * 64, cur ^ 1);  // issue next tile (wraps at end)

    // ---- QK^T: ST[sub][r] = S[kv = sub*32+(r&3)+8(r>>2)+4hi][q = l31] ----
    f32x16 st[2];
#pragma unroll
    for (int sub = 0; sub < 2; sub++) {
      f32x16 z = {};
      const int krow = sub * 32 + l31;
#pragma unroll
      for (int ks = 0; ks < 8; ks++) {
        const int pos = (2 * ks + hi) ^ (l31 & 15);
        bf16x8 kf = *(const bf16x8*)&Ks[cur][krow * 128 + pos * 8];
        z = __builtin_amdgcn_mfma_f32_32x32x16_bf16(kf, qf[ks], z, 0, 0, 0);
      }
      st[sub] = z;
    }

    // ---- in-register online softmax (q = l31 per lane, log2 domain) ----
    float red[16];
#pragma unroll
    for (int r = 0; r < 16; r++) red[r] = fmaxf(st[0][r], st[1][r]);
#pragma unroll
    for (int w = 8; w >= 1; w >>= 1)
#pragma unroll
      for (int r = 0; r < w; r++) red[r] = fmaxf(red[r], red[r + w]);
    float tm = fmaxf(red[0], __shfl_xor(red[0], 32));

    if (!__all(tm <= mrun + 8.0f)) {  // defer-rescale THR=8 (log2)
      float mnew = fmaxf(mrun, tm);
      float sc = __builtin_amdgcn_exp2f(mrun - mnew);
      mrun = mnew;
      lrun *= sc;
#pragma unroll
      for (int r = 0; r < 16; r++) {
        float scr = __shfl(sc, (r & 3) + 8 * (r >> 2) + 4 * hi);
#pragma unroll
        for (int dt = 0; dt < 4; dt++) oacc[dt][r] *= scr;
      }
    }

#pragma unroll
    for (int r = 0; r < 16; r++) {
      st[0][r] = __builtin_amdgcn_exp2f(st[0][r] - mrun);
      st[1][r] = __builtin_amdgcn_exp2f(st[1][r] - mrun);
      red[r] = st[0][r] + st[1][r];
    }
#pragma unroll
    for (int w = 8; w >= 1; w >>= 1)
#pragma unroll
      for (int r = 0; r < w; r++) red[r] += red[r + w];
    float ps = red[0] + __shfl_xor(red[0], 32);
    lrun += ps;

    // ---- pack P -> PV A-frags (kv k-steps ks2 = sub*2 + h2) ----
    bf16x8 paw[4];
#pragma unroll
    for (int sub = 0; sub < 2; sub++)
#pragma unroll
      for (int h2 = 0; h2 < 2; h2++) {
        unsigned int a0 = pk2bf(st[sub][8 * h2 + 0], st[sub][8 * h2 + 1]);
        unsigned int a1 = pk2bf(st[sub][8 * h2 + 2], st[sub][8 * h2 + 3]);
        unsigned int b0 = pk2bf(st[sub][8 * h2 + 4], st[sub][8 * h2 + 5]);
        unsigned int b1 = pk2bf(st[sub][8 * h2 + 6], st[sub][8 * h2 + 7]);
        unsigned int s0 = hi ? a0 : b0;  // what partner needs from me
        unsigned int s1 = hi ? a1 : b1;
        unsigned int r0 = (unsigned int)__shfl_xor((int)s0, 32);
        unsigned int r1 = (unsigned int)__shfl_xor((int)s1, 32);
        int4v w;
        w.x = (int)(hi ? r0 : a0);
        w.y = (int)(hi ? r1 : a1);
        w.z = (int)(hi ? b0 : r0);
        w.w = (int)(hi ? b1 : r1);
        paw[sub * 2 + h2] = __builtin_bit_cast(bf16x8, w);
      }

    // ---- PV: O[q][dt*32+l31] += P · V ----
#pragma unroll
    for (int dt = 0; dt < 4; dt++) {
      f32x16 z = oacc[dt];
      const int sR = dt * 16 + (l31 >> 1);  // superrow of d = dt*32+l31
#pragma unroll
      for (int ks2 = 0; ks2 < 4; ks2++) {
        const int slot = (2 * ks2 + hi + 8 * (l31 & 1)) ^ (l31 >> 1);
        bf16x8 vfr = *(const bf16x8*)&Vs[cur][sR * 128 + slot * 8];
        z = __builtin_amdgcn_mfma_f32_32x32x16_bf16(paw[ks2], vfr, z, 0, 0, 0);
      }
      oacc[dt] = z;
    }

    asm volatile("s_waitcnt vmcnt(0)" ::: "memory");  // next tile landed
    __builtin_amdgcn_sched_barrier(0);
    __builtin_amdgcn_s_barrier();
  }

  // epilogue: normalize by row-sum (broadcast lrun from lane q) and store
  float inv = 1.0f / lrun;
#pragma unroll
  for (int r = 0; r < 16; r++) {
    const int qrow = (r & 3) + 8 * (r >> 2) + 4 * hi;
    float invr = __shfl(inv, qrow);
    size_t row = (size_t)(b * 2048 + q0 + qrow);
#pragma unroll
    for (int dt = 0; dt < 4; dt++)
      Ob[row * 2048 + h * 128 + dt * 32 + l31] = f2bf(oacc[dt][r] * invr);
  }
}

// ---------------------------------------------------------------------------
extern "C" void kernel_launch(void* const* d_in, const int* in_sizes, int n_in,
                              void* d_out, int out_size, void* d_ws,
                              size_t ws_size, hipStream_t stream) {
  const float* x = (const float*)d_in[0];
  const float* Wq = (const float*)d_in[1];
  const float* Wk = (const float*)d_in[2];
  const float* Wv = (const float*)d_in[3];
  const float* Wo = (const float*)d_in[4];
  const float* bo = (const float*)d_in[5];

  const int Bb = 2, Lq = 2048, D = 2048, DH = 128;
  const int M = Bb * Lq;  // 4096

  char* ws = (char*)d_ws;
  size_t off = 0;
  auto alloc = [&](size_t bytes) {
    void* p = ws + off;
    off += (bytes + 255) & ~size_t(255);
    return p;
  };
  unsigned short* x_bf = (unsigned short*)alloc((size_t)M * D * 2);
  unsigned short* Wq_bf = (unsigned short*)alloc((size_t)D * D * 2);
  unsigned short* Wkv_bf = (unsigned short*)alloc((size_t)2 * DH * D * 2);
  unsigned short* Wo_bf = (unsigned short*)alloc((size_t)D * D * 2);
  unsigned short* Qbuf = (unsigned short*)alloc((size_t)M * D * 2);
  unsigned short* Kbuf = (unsigned short*)alloc((size_t)M * DH * 2);
  unsigned short* VTbuf = (unsigned short*)alloc((size_t)DH * M * 2);
  unsigned short* AObuf = (unsigned short*)alloc((size_t)M * D * 2);

  auto cast = [&](const float* in, unsigned short* outp, int n) {
    int n4 = n >> 2;
    int grid = (n4 + 255) / 256;
    if (grid > 2048) grid = 2048;
    cast_bf16_kernel<<<grid, 256, 0, stream>>>(in, outp, n4);
  };
  cast(x, x_bf, M * D);
  cast(Wq, Wq_bf, D * D);
  cast(Wk, Wkv_bf, DH * D);                   // rows 0..127 of fused KV
  cast(Wv, Wkv_bf + (size_t)DH * D, DH * D);  // rows 128..255
  cast(Wo, Wo_bf, D * D);

  // Q = x·Wq^T scaled by log2(e)/sqrt(dh): logits land in exp2 domain
  gemm_bt<0><<<dim3(M / 128, D / 128), 256, 0, stream>>>(
      x_bf, Wq_bf, Qbuf, M, D, D, 0.12752041986f, nullptr, nullptr);
  // K and V^T in one GEMM (N=256)
  gemm_bt<3><<<dim3(M / 128, 2), 256, 0, stream>>>(
      x_bf, Wkv_bf, Kbuf, M, 2 * DH, D, 1.0f, nullptr, VTbuf);
  // attention
  mqa_attn<<<dim3(Lq / 128, Bb * 16), 256, 0, stream>>>(Qbuf, Kbuf, VTbuf,
                                                        AObuf);
  // out = AO·Wo^T + bo  (fp32 output)
  gemm_bt<2><<<dim3(M / 128, D / 128), 256, 0, stream>>>(
      AObuf, Wo_bf, d_out, M, D, D, 1.0f, bo, nullptr);
}

// Round 7
// 278.749 us; speedup vs baseline: 2.2902x; 1.0938x over previous
//
#include <hip/hip_runtime.h>

// ---------------------------------------------------------------------------
// MQA forward: out = OutProj( MHA( x·Wq^T, x·Wk^T, x·Wv^T ) )
// B=2, L=2048, D=2048, H=16, dh=128 (MQA: K/V shared across heads)
// R7: R6 + (a) v_cvt_pk_bf16_f32 for P pack (~110 VALU ops -> 16/iter),
// (b) s_setprio around MFMA clusters (T5), (c) Q/K/V^T projections fused
// into ONE GEMM launch (N=2304, MODE 4 epilogue).
// ---------------------------------------------------------------------------

typedef __attribute__((ext_vector_type(8))) short bf16x8;
typedef __attribute__((ext_vector_type(4))) short short4v;
typedef __attribute__((ext_vector_type(4))) float f32x4;
typedef __attribute__((ext_vector_type(16))) float f32x16;
typedef __attribute__((ext_vector_type(4))) int int4v;

__device__ __forceinline__ unsigned short f2bf(float f) {
  unsigned int u = __builtin_bit_cast(unsigned int, f);
  u += 0x7fffu + ((u >> 16) & 1u);  // RNE (finite inputs only)
  return (unsigned short)(u >> 16);
}

// packed f32 pair -> 2x bf16 in one dword (hardware RNE pack)
__device__ __forceinline__ unsigned int cvtpk(float lo, float hi) {
  unsigned int r;
  asm("v_cvt_pk_bf16_f32 %0, %1, %2" : "=v"(r) : "v"(lo), "v"(hi));
  return r;
}

typedef __attribute__((address_space(1))) void gvoid_t;
typedef __attribute__((address_space(3))) void lvoid_t;

__device__ __forceinline__ void gll16(const void* g, void* l) {
  __builtin_amdgcn_global_load_lds((gvoid_t*)g, (lvoid_t*)l, 16, 0, 0);
}

// ---------------------------------------------------------------------------
// fp32 -> bf16 cast, vectorized 4-wide
// ---------------------------------------------------------------------------
__global__ void cast_bf16_kernel(const float* __restrict__ in,
                                 unsigned short* __restrict__ out, int n4) {
  int i = blockIdx.x * blockDim.x + threadIdx.x;
  int stride = gridDim.x * blockDim.x;
  for (; i < n4; i += stride) {
    float4 f = reinterpret_cast<const float4*>(in)[i];
    short4v o;
    o.x = (short)f2bf(f.x);
    o.y = (short)f2bf(f.y);
    o.z = (short)f2bf(f.z);
    o.w = (short)f2bf(f.w);
    reinterpret_cast<short4v*>(out)[i] = o;
  }
}

// ---------------------------------------------------------------------------
// GEMM: C[M,N] = A[M,K] · B[N,K]^T   (bf16 in, fp32 acc)
// MODE 0: bf16 store C[m*N+n] * scale
// MODE 2: fp32 store C[m*N+n] + bias[n]
// MODE 4: fused QKV: col<2048 -> Q bf16 *scale (stride 2048);
//         col<2176 -> K bf16 (stride 128); else -> V^T bf16 (transposed)
// ---------------------------------------------------------------------------
template <int MODE>
__global__ __launch_bounds__(256) void gemm_bt(
    const unsigned short* __restrict__ A, const unsigned short* __restrict__ B,
    void* __restrict__ Cout, int M, int N, int K, float scale,
    const float* __restrict__ bias, void* __restrict__ C2,
    void* __restrict__ C3) {
  __shared__ unsigned short As[128 * 32] __attribute__((aligned(16)));
  __shared__ unsigned short Bs[128 * 32] __attribute__((aligned(16)));

  const int tid = threadIdx.x;
  const int lane = tid & 63;
  const int wave = tid >> 6;
  const int lr = lane & 15;
  const int lg = lane >> 4;
  const int bm = blockIdx.x * 128;
  const int bn = blockIdx.y * 128;
  const int wrow = (wave >> 1) * 64;
  const int wcol = (wave & 1) * 64;

  f32x4 acc[4][4] = {};

  const int c0 = tid;
  const int c1 = tid + 256;

  for (int k0 = 0; k0 < K; k0 += 32) {
    __syncthreads();
    gll16(A + (size_t)(bm + (c0 >> 2)) * K + k0 + (c0 & 3) * 8,
          (char*)As + wave * 1024);
    gll16(A + (size_t)(bm + (c1 >> 2)) * K + k0 + (c1 & 3) * 8,
          (char*)As + 4096 + wave * 1024);
    gll16(B + (size_t)(bn + (c0 >> 2)) * K + k0 + (c0 & 3) * 8,
          (char*)Bs + wave * 1024);
    gll16(B + (size_t)(bn + (c1 >> 2)) * K + k0 + (c1 & 3) * 8,
          (char*)Bs + 4096 + wave * 1024);
    __syncthreads();

    bf16x8 af[4], bfr[4];
#pragma unroll
    for (int mi = 0; mi < 4; mi++)
      af[mi] = *(const bf16x8*)&As[(wrow + mi * 16 + lr) * 32 + 8 * lg];
#pragma unroll
    for (int nj = 0; nj < 4; nj++)
      bfr[nj] = *(const bf16x8*)&Bs[(wcol + nj * 16 + lr) * 32 + 8 * lg];
#pragma unroll
    for (int mi = 0; mi < 4; mi++)
#pragma unroll
      for (int nj = 0; nj < 4; nj++)
        acc[mi][nj] = __builtin_amdgcn_mfma_f32_16x16x32_bf16(
            af[mi], bfr[nj], acc[mi][nj], 0, 0, 0);
  }

#pragma unroll
  for (int mi = 0; mi < 4; mi++)
#pragma unroll
    for (int nj = 0; nj < 4; nj++) {
      const int row = bm + wrow + mi * 16 + lg * 4;
      const int col = bn + wcol + nj * 16 + lr;
#pragma unroll
      for (int r = 0; r < 4; r++) {
        float v = acc[mi][nj][r];
        if constexpr (MODE == 0) {
          ((unsigned short*)Cout)[(size_t)(row + r) * N + col] =
              f2bf(v * scale);
        } else if constexpr (MODE == 2) {
          ((float*)Cout)[(size_t)(row + r) * N + col] = v + bias[col];
        } else {  // MODE 4: fused Q / K / V^T epilogue
          if (col < 2048)
            ((unsigned short*)Cout)[(size_t)(row + r) * 2048 + col] =
                f2bf(v * scale);
          else if (col < 2176)
            ((unsigned short*)C2)[(size_t)(row + r) * 128 + (col - 2048)] =
                f2bf(v);
          else
            ((unsigned short*)C3)[(size_t)(col - 2176) * M + (row + r)] =
                f2bf(v);
        }
      }
    }
}

// ---------------------------------------------------------------------------
// Flash-style MQA attention, v7 (v6 + cvt_pk pack + setprio).
// Q: [B*L, 2048] bf16 pre-scaled by log2(e)/sqrt(dh)  (exp2-domain logits)
// K: [B*L, 128] bf16 ; VT: [128, B*L] bf16
// O: [B*L, 2048] bf16
// Block 256 = 4 waves sharing one (b,h); each wave owns 32 q-rows.
// K tile LDS: [64 rows][16 chunks], chunk pos = c ^ (row&15)
// V tile LDS: [64 superrows(d/2)][16 slots], slot = (c+8*(d&1)) ^ ((d>>1)&15)
// Double-buffered; stage next tile at iter top, vmcnt(0)+barrier at iter end.
// grid: (L/128, B*H) = (16, 32)
// ---------------------------------------------------------------------------
__global__ __launch_bounds__(256) void mqa_attn(
    const unsigned short* __restrict__ Q, const unsigned short* __restrict__ Kb,
    const unsigned short* __restrict__ VT, unsigned short* __restrict__ Ob) {
  __shared__ unsigned short Ks[2][64 * 128] __attribute__((aligned(16)));
  __shared__ unsigned short Vs[2][64 * 128] __attribute__((aligned(16)));

  const int tid = threadIdx.x;
  const int lane = tid & 63;
  const int wave = tid >> 6;
  const int l31 = lane & 31;
  const int hi = lane >> 5;
  const int bh = blockIdx.y;
  const int b = bh >> 4;
  const int h = bh & 15;
  const int q0 = blockIdx.x * 128 + wave * 32;

  const unsigned short* Qb = Q + ((size_t)(b * 2048 + q0)) * 2048 + h * 128;
  const unsigned short* Kbase = Kb + (size_t)b * 2048 * 128;
  const unsigned short* VTb = VT + (size_t)b * 2048;

  // Q B-frags: q = l31, d = 16*ks + 8*hi + i   (8 k-steps over dh=128)
  bf16x8 qf[8];
#pragma unroll
  for (int ks = 0; ks < 8; ks++)
    qf[ks] = *(const bf16x8*)&Qb[(size_t)l31 * 2048 + ks * 16 + hi * 8];

  f32x16 oacc[4] = {};  // O[q][d]: col d = dt*32+l31, row q=(r&3)+8(r>>2)+4hi
  float mrun = -1e30f, lrun = 0.0f;

  // staging source offsets (elements), inverse of the LDS placement
  int koff[4], voff[4];
#pragma unroll
  for (int t = 0; t < 4; t++) {
    int ci = t * 256 + tid;           // linear 16B chunk id 0..1023
    int krow = ci >> 4;
    int kc = (ci ^ krow) & 15;        // global chunk col = pos ^ (row&15)
    koff[t] = krow * 128 + kc * 8;
    int s = ci >> 4;                  // V superrow
    int u = (ci ^ s) & 15;            // (slot) ^ (s&15)
    voff[t] = (2 * s + (u >> 3)) * 4096 + (u & 7) * 8;
  }

  auto stage = [&](int kv0, int bsel) {
#pragma unroll
    for (int t = 0; t < 4; t++) {
      gll16(Kbase + (size_t)kv0 * 128 + koff[t],
            (char*)&Ks[bsel][0] + t * 4096 + wave * 1024);
      gll16(VTb + kv0 + voff[t],
            (char*)&Vs[bsel][0] + t * 4096 + wave * 1024);
    }
  };

  // prologue: tile 0 into buffer 0
  stage(0, 0);
  asm volatile("s_waitcnt vmcnt(0)" ::: "memory");
  __builtin_amdgcn_sched_barrier(0);
  __builtin_amdgcn_s_barrier();

  for (int t = 0; t < 32; t++) {
    const int cur = t & 1;
    stage(((t + 1) & 31) * 64, cur ^ 1);  // issue next tile (wraps at end)

    // ---- QK^T: ST[sub][r] = S[kv = sub*32+(r&3)+8(r>>2)+4hi][q = l31] ----
    f32x16 st[2];
    __builtin_amdgcn_s_setprio(1);
#pragma unroll
    for (int sub = 0; sub < 2; sub++) {
      f32x16 z = {};
      const int krow = sub * 32 + l31;
#pragma unroll
      for (int ks = 0; ks < 8; ks++) {
        const int pos = (2 * ks + hi) ^ (l31 & 15);
        bf16x8 kf = *(const bf16x8*)&Ks[cur][krow * 128 + pos * 8];
        z = __builtin_amdgcn_mfma_f32_32x32x16_bf16(kf, qf[ks], z, 0, 0, 0);
      }
      st[sub] = z;
    }
    __builtin_amdgcn_s_setprio(0);

    // ---- in-register online softmax (q = l31 per lane, log2 domain) ----
    float red[16];
#pragma unroll
    for (int r = 0; r < 16; r++) red[r] = fmaxf(st[0][r], st[1][r]);
    // 16 -> 6 -> 2 -> 1 via max3 where possible
    {
      float u0 = fmaxf(fmaxf(red[0], red[1]), red[2]);
      float u1 = fmaxf(fmaxf(red[3], red[4]), red[5]);
      float u2 = fmaxf(fmaxf(red[6], red[7]), red[8]);
      float u3 = fmaxf(fmaxf(red[9], red[10]), red[11]);
      float u4 = fmaxf(fmaxf(red[12], red[13]), red[14]);
      red[0] = fmaxf(fmaxf(fmaxf(u0, u1), u2),
                     fmaxf(fmaxf(u3, u4), red[15]));
    }
    float tm = fmaxf(red[0], __shfl_xor(red[0], 32));

    if (!__all(tm <= mrun + 8.0f)) {  // defer-rescale THR=8 (log2)
      float mnew = fmaxf(mrun, tm);
      float sc = __builtin_amdgcn_exp2f(mrun - mnew);
      mrun = mnew;
      lrun *= sc;
#pragma unroll
      for (int r = 0; r < 16; r++) {
        float scr = __shfl(sc, (r & 3) + 8 * (r >> 2) + 4 * hi);
#pragma unroll
        for (int dt = 0; dt < 4; dt++) oacc[dt][r] *= scr;
      }
    }

#pragma unroll
    for (int r = 0; r < 16; r++) {
      st[0][r] = __builtin_amdgcn_exp2f(st[0][r] - mrun);
      st[1][r] = __builtin_amdgcn_exp2f(st[1][r] - mrun);
      red[r] = st[0][r] + st[1][r];
    }
#pragma unroll
    for (int w = 8; w >= 1; w >>= 1)
#pragma unroll
      for (int r = 0; r < w; r++) red[r] += red[r + w];
    float ps = red[0] + __shfl_xor(red[0], 32);
    lrun += ps;

    // ---- pack P -> PV A-frags via v_cvt_pk_bf16_f32 ----
    bf16x8 paw[4];
#pragma unroll
    for (int sub = 0; sub < 2; sub++)
#pragma unroll
      for (int h2 = 0; h2 < 2; h2++) {
        unsigned int a0 = cvtpk(st[sub][8 * h2 + 0], st[sub][8 * h2 + 1]);
        unsigned int a1 = cvtpk(st[sub][8 * h2 + 2], st[sub][8 * h2 + 3]);
        unsigned int b0 = cvtpk(st[sub][8 * h2 + 4], st[sub][8 * h2 + 5]);
        unsigned int b1 = cvtpk(st[sub][8 * h2 + 6], st[sub][8 * h2 + 7]);
        unsigned int s0 = hi ? a0 : b0;  // what partner needs from me
        unsigned int s1 = hi ? a1 : b1;
        unsigned int r0 = (unsigned int)__shfl_xor((int)s0, 32);
        unsigned int r1 = (unsigned int)__shfl_xor((int)s1, 32);
        int4v w;
        w.x = (int)(hi ? r0 : a0);
        w.y = (int)(hi ? r1 : a1);
        w.z = (int)(hi ? b0 : r0);
        w.w = (int)(hi ? b1 : r1);
        paw[sub * 2 + h2] = __builtin_bit_cast(bf16x8, w);
      }

    // ---- PV: O[q][dt*32+l31] += P · V ----
    __builtin_amdgcn_s_setprio(1);
#pragma unroll
    for (int dt = 0; dt < 4; dt++) {
      f32x16 z = oacc[dt];
      const int sR = dt * 16 + (l31 >> 1);  // superrow of d = dt*32+l31
#pragma unroll
      for (int ks2 = 0; ks2 < 4; ks2++) {
        const int slot = (2 * ks2 + hi + 8 * (l31 & 1)) ^ (l31 >> 1);
        bf16x8 vfr = *(const bf16x8*)&Vs[cur][sR * 128 + slot * 8];
        z = __builtin_amdgcn_mfma_f32_32x32x16_bf16(paw[ks2], vfr, z, 0, 0, 0);
      }
      oacc[dt] = z;
    }
    __builtin_amdgcn_s_setprio(0);

    asm volatile("s_waitcnt vmcnt(0)" ::: "memory");  // next tile landed
    __builtin_amdgcn_sched_barrier(0);
    __builtin_amdgcn_s_barrier();
  }

  // epilogue: normalize by row-sum (broadcast lrun from lane q) and store
  float inv = 1.0f / lrun;
#pragma unroll
  for (int r = 0; r < 16; r++) {
    const int qrow = (r & 3) + 8 * (r >> 2) + 4 * hi;
    float invr = __shfl(inv, qrow);
    size_t row = (size_t)(b * 2048 + q0 + qrow);
#pragma unroll
    for (int dt = 0; dt < 4; dt++)
      Ob[row * 2048 + h * 128 + dt * 32 + l31] = f2bf(oacc[dt][r] * invr);
  }
}

// ---------------------------------------------------------------------------
extern "C" void kernel_launch(void* const* d_in, const int* in_sizes, int n_in,
                              void* d_out, int out_size, void* d_ws,
                              size_t ws_size, hipStream_t stream) {
  const float* x = (const float*)d_in[0];
  const float* Wq = (const float*)d_in[1];
  const float* Wk = (const float*)d_in[2];
  const float* Wv = (const float*)d_in[3];
  const float* Wo = (const float*)d_in[4];
  const float* bo = (const float*)d_in[5];

  const int Bb = 2, Lq = 2048, D = 2048, DH = 128;
  const int M = Bb * Lq;  // 4096

  char* ws = (char*)d_ws;
  size_t off = 0;
  auto alloc = [&](size_t bytes) {
    void* p = ws + off;
    off += (bytes + 255) & ~size_t(255);
    return p;
  };
  unsigned short* x_bf = (unsigned short*)alloc((size_t)M * D * 2);
  unsigned short* Wall_bf = (unsigned short*)alloc((size_t)2304 * D * 2);
  unsigned short* Wo_bf = (unsigned short*)alloc((size_t)D * D * 2);
  unsigned short* Qbuf = (unsigned short*)alloc((size_t)M * D * 2);
  unsigned short* Kbuf = (unsigned short*)alloc((size_t)M * DH * 2);
  unsigned short* VTbuf = (unsigned short*)alloc((size_t)DH * M * 2);
  unsigned short* AObuf = (unsigned short*)alloc((size_t)M * D * 2);

  auto cast = [&](const float* in, unsigned short* outp, int n) {
    int n4 = n >> 2;
    int grid = (n4 + 255) / 256;
    if (grid > 2048) grid = 2048;
    cast_bf16_kernel<<<grid, 256, 0, stream>>>(in, outp, n4);
  };
  cast(x, x_bf, M * D);
  cast(Wq, Wall_bf, D * D);                          // rows 0..2047
  cast(Wk, Wall_bf + (size_t)2048 * D, DH * D);      // rows 2048..2175
  cast(Wv, Wall_bf + (size_t)2176 * D, DH * D);      // rows 2176..2303
  cast(Wo, Wo_bf, D * D);

  // Q (scaled by log2(e)/sqrt(dh)), K, V^T in ONE GEMM (N=2304)
  gemm_bt<4><<<dim3(M / 128, 2304 / 128), 256, 0, stream>>>(
      x_bf, Wall_bf, Qbuf, M, 2304, D, 0.12752041986f, nullptr, Kbuf, VTbuf);
  // attention
  mqa_attn<<<dim3(Lq / 128, Bb * 16), 256, 0, stream>>>(Qbuf, Kbuf, VTbuf,
                                                        AObuf);
  // out = AO·Wo^T + bo  (fp32 output)
  gemm_bt<2><<<dim3(M / 128, D / 128), 256, 0, stream>>>(
      AObuf, Wo_bf, d_out, M, D, D, 1.0f, bo, nullptr, nullptr);
}